// Round 4
// baseline (289.018 us; speedup 1.0000x reference)
//
#include <hip/hip_runtime.h>
#include <math.h>

#define N_NODES 50000
#define N_EDGES 640000
#define FDIM 128
#define NCLS 16
#define BN_EPS 1e-5f

// ---- bf16 pack/unpack (RNE) ----
__device__ __forceinline__ unsigned pack_bf16x2(float lo, float hi) {
    unsigned ul = __float_as_uint(lo);
    unsigned uh = __float_as_uint(hi);
    ul += 0x7fff + ((ul >> 16) & 1);
    uh += 0x7fff + ((uh >> 16) & 1);
    return (ul >> 16) | (uh & 0xffff0000u);
}
__device__ __forceinline__ float bf_lo(unsigned u) { return __uint_as_float(u << 16); }
__device__ __forceinline__ float bf_hi(unsigned u) { return __uint_as_float(u & 0xffff0000u); }

__device__ __forceinline__ void accum8(float* acc, uint4 u, float wgt) {
    acc[0] += bf_lo(u.x) * wgt; acc[1] += bf_hi(u.x) * wgt;
    acc[2] += bf_lo(u.y) * wgt; acc[3] += bf_hi(u.y) * wgt;
    acc[4] += bf_lo(u.z) * wgt; acc[5] += bf_hi(u.z) * wgt;
    acc[6] += bf_lo(u.w) * wgt; acc[7] += bf_hi(u.w) * wgt;
}

// ---------------- CSR build ----------------

__global__ __launch_bounds__(256) void count_deg_kernel(const int* __restrict__ dst, int* __restrict__ deg) {
    int gid = blockIdx.x * 256 + threadIdx.x;
    if (gid < N_EDGES) atomicAdd(&deg[dst[gid]], 1);
}

__global__ __launch_bounds__(256) void scan_block_kernel(const int* __restrict__ deg,
                                                         int* __restrict__ offs,
                                                         int* __restrict__ partials,
                                                         float* __restrict__ dinv) {
    __shared__ int s[256];
    int tid = threadIdx.x;
    int gid = blockIdx.x * 256 + tid;
    int v = (gid < N_NODES) ? deg[gid] : 0;
    if (gid < N_NODES) dinv[gid] = rsqrtf((float)(v + 1));  // +1 self loop
    s[tid] = v;
    __syncthreads();
    for (int off = 1; off < 256; off <<= 1) {
        int t = (tid >= off) ? s[tid - off] : 0;
        __syncthreads();
        s[tid] += t;
        __syncthreads();
    }
    if (gid <= N_NODES) offs[gid] = s[tid] - v;   // block-local exclusive
    if (tid == 255) partials[blockIdx.x] = s[255];
}

__global__ __launch_bounds__(256) void scan_partials_kernel(int* __restrict__ partials, int nb) {
    __shared__ int s[256];
    int tid = threadIdx.x;
    int v = (tid < nb) ? partials[tid] : 0;
    s[tid] = v;
    __syncthreads();
    for (int off = 1; off < 256; off <<= 1) {
        int t = (tid >= off) ? s[tid - off] : 0;
        __syncthreads();
        s[tid] += t;
        __syncthreads();
    }
    if (tid < nb) partials[tid] = s[tid] - v;
}

__global__ __launch_bounds__(256) void fill_csr_kernel(const int* __restrict__ src,
                                                       const int* __restrict__ dst,
                                                       const int* __restrict__ offs,
                                                       const int* __restrict__ part,
                                                       const float* __restrict__ dinv,
                                                       int* __restrict__ cursor,
                                                       int2* __restrict__ csr_sw) {
    int gid = blockIdx.x * 256 + threadIdx.x;
    if (gid < N_EDGES) {
        int d = dst[gid];
        int s = src[gid];
        int pos = offs[d] + part[d >> 8] + atomicAdd(&cursor[d], 1);
        csr_sw[pos] = make_int2(s, __float_as_int(dinv[s]));
    }
}

// ---------------- fold: W2c = W2@Wc, bc2 = b2@Wc + bc, fused BN affine ----------------
__global__ __launch_bounds__(256) void fold_w_kernel(const float* __restrict__ W2,
                                                     const float* __restrict__ Wc,
                                                     const float* __restrict__ b1,
                                                     const float* __restrict__ b2,
                                                     const float* __restrict__ bc,
                                                     const float* __restrict__ gamma,
                                                     const float* __restrict__ beta,
                                                     const float* __restrict__ rmean,
                                                     const float* __restrict__ rvar,
                                                     float* __restrict__ W2c,
                                                     float* __restrict__ bc2,
                                                     float4* __restrict__ fusedq) {
    int gid = blockIdx.x * 256 + threadIdx.x;  // 0..2047
    int r = gid >> 4, c = gid & 15;
    float acc = 0.f;
#pragma unroll 8
    for (int k = 0; k < 128; k++) acc += W2[r * 128 + k] * Wc[k * 16 + c];
    W2c[gid] = acc;
    if (blockIdx.x == 0) {
        int tid = threadIdx.x;
        if (tid < 16) {
            float a = bc[tid];
            for (int k = 0; k < 128; k++) a += b2[k] * Wc[k * 16 + tid];
            bc2[tid] = a;
        }
        if (tid < 64) {
            int c0 = tid * 2, c1 = c0 + 1;
            float sc0 = gamma[c0] * rsqrtf(rvar[c0] + BN_EPS);
            float sc1 = gamma[c1] * rsqrtf(rvar[c1] + BN_EPS);
            float sh0 = (b1[c0] - rmean[c0]) * sc0 + beta[c0];
            float sh1 = (b1[c1] - rmean[c1]) * sc1 + beta[c1];
            fusedq[tid] = make_float4(sc0, sh0, sc1, sh1);
        }
    }
}

// ---------------- GEMM 50000x128 @ 128x128 -> bf16 out ----------------
__global__ __launch_bounds__(256) void gemm128_kernel(const float* __restrict__ X,
                                                      const float* __restrict__ W,
                                                      unsigned* __restrict__ Yb, int M) {
    __shared__ float sX[64 * 33];
    __shared__ float sW[32 * 128];
    int tid = threadIdx.x;
    int r0 = blockIdx.x * 64;
    int colg = tid & 15, rowt = tid >> 4;

    float acc[4][8];
#pragma unroll
    for (int i = 0; i < 4; i++)
#pragma unroll
        for (int j = 0; j < 8; j++) acc[i][j] = 0.f;

    const float4* X4 = (const float4*)X;
    const float4* W4 = (const float4*)W;
    float4* sW4 = (float4*)sW;

#pragma unroll
    for (int kt = 0; kt < 4; kt++) {
#pragma unroll
        for (int i = 0; i < 2; i++) {
            int idx = tid + i * 256;
            int row = idx >> 3, k4 = idx & 7;
            float4 v = make_float4(0.f, 0.f, 0.f, 0.f);
            if (r0 + row < M) v = X4[(size_t)(r0 + row) * 32 + kt * 8 + k4];
            float* p = &sX[row * 33 + k4 * 4];
            p[0] = v.x; p[1] = v.y; p[2] = v.z; p[3] = v.w;
        }
#pragma unroll
        for (int i = 0; i < 4; i++) {
            int idx = tid + i * 256;
            int kk = idx >> 5, c4 = idx & 31;
            sW4[kk * 32 + c4] = W4[(size_t)(kt * 32 + kk) * 32 + c4];
        }
        __syncthreads();

#pragma unroll 8
        for (int k = 0; k < 32; k++) {
            float4 w0 = sW4[k * 32 + colg * 2];
            float4 w1 = sW4[k * 32 + colg * 2 + 1];
            float xs[4];
#pragma unroll
            for (int i = 0; i < 4; i++) xs[i] = sX[(rowt * 4 + i) * 33 + k];
#pragma unroll
            for (int i = 0; i < 4; i++) {
                acc[i][0] += xs[i] * w0.x; acc[i][1] += xs[i] * w0.y;
                acc[i][2] += xs[i] * w0.z; acc[i][3] += xs[i] * w0.w;
                acc[i][4] += xs[i] * w1.x; acc[i][5] += xs[i] * w1.y;
                acc[i][6] += xs[i] * w1.z; acc[i][7] += xs[i] * w1.w;
            }
        }
        __syncthreads();
    }

#pragma unroll
    for (int i = 0; i < 4; i++) {
        int row = r0 + rowt * 4 + i;
        if (row < M) {
            uint4 pv;
            pv.x = pack_bf16x2(acc[i][0], acc[i][1]);
            pv.y = pack_bf16x2(acc[i][2], acc[i][3]);
            pv.z = pack_bf16x2(acc[i][4], acc[i][5]);
            pv.w = pack_bf16x2(acc[i][6], acc[i][7]);
            *((uint4*)(Yb + (size_t)row * 64 + colg * 4)) = pv;
        }
    }
}

// ---------------- Layer-1 agg: 16-lane-group row gather + BN + ReLU + @W2c -> Z ----------------
// Wave layout: c16 = lane&15 owns features c16*8..+7; g = lane>>4 is edge slot (4 edges/load).
__global__ __launch_bounds__(256) void agg1_kernel(const uint4* __restrict__ Hb4,
                                                   const int2* __restrict__ csr_sw,
                                                   const int* __restrict__ offs,
                                                   const int* __restrict__ part,
                                                   const float* __restrict__ dinv,
                                                   const float4* __restrict__ fusedq,
                                                   const float* __restrict__ W2c,
                                                   float* __restrict__ Z) {
    int wv = threadIdx.x >> 6, l = threadIdx.x & 63;
    int node = blockIdx.x * 4 + wv;            // 12500*4 == 50000
    int beg = offs[node] + part[node >> 8];
    int end = offs[node + 1] + part[(node + 1) >> 8];
    float di = dinv[node];
    int c16 = l & 15, g = l >> 4;

    // W2c slice: features c16*8..+7 x classes g*4..+3 (8 float4 loads)
    float wreg[8][4];
#pragma unroll
    for (int j = 0; j < 8; j++) {
        float4 t = *(const float4*)&W2c[(c16 * 8 + j) * 16 + g * 4];
        wreg[j][0] = t.x; wreg[j][1] = t.y; wreg[j][2] = t.z; wreg[j][3] = t.w;
    }

    float acc[8];
#pragma unroll
    for (int j = 0; j < 8; j++) acc[j] = 0.f;

    int e = beg;
    for (; e + 8 <= end; e += 8) {             // 8 edges/wave-iter, 2 row-loads in flight
        int2 sw0 = csr_sw[e + g];
        int2 sw1 = csr_sw[e + 4 + g];
        uint4 r0 = Hb4[(size_t)sw0.x * 16 + c16];
        uint4 r1 = Hb4[(size_t)sw1.x * 16 + c16];
        float w0 = __int_as_float(sw0.y) * di;
        float w1 = __int_as_float(sw1.y) * di;
        accum8(acc, r0, w0);
        accum8(acc, r1, w1);
    }
    for (; e < end; e += 4) {                  // masked tail, 4 edges/iter
        int ee = e + g;
        int idx = (ee < end) ? ee : (end - 1);
        int2 sw = csr_sw[idx];
        float wgt = (ee < end) ? __int_as_float(sw.y) * di : 0.f;
        uint4 r = Hb4[(size_t)sw.x * 16 + c16];
        accum8(acc, r, wgt);
    }

    // fold the 4 edge-slot partials
#pragma unroll
    for (int j = 0; j < 8; j++) {
        acc[j] += __shfl_xor(acc[j], 16);
        acc[j] += __shfl_xor(acc[j], 32);
    }
    // self loop (identical add in every slot group -> stays consistent)
    uint4 sr = Hb4[(size_t)node * 16 + c16];
    accum8(acc, sr, di * di);

    // fused BN affine + ReLU
#pragma unroll
    for (int j2 = 0; j2 < 4; j2++) {
        float4 qv = fusedq[c16 * 4 + j2];
        acc[j2 * 2]     = fmaxf(acc[j2 * 2]     * qv.x + qv.y, 0.f);
        acc[j2 * 2 + 1] = fmaxf(acc[j2 * 2 + 1] * qv.z + qv.w, 0.f);
    }

    // Z partials: group g computes classes g*4..+3
    float p0 = 0.f, p1 = 0.f, p2 = 0.f, p3 = 0.f;
#pragma unroll
    for (int j = 0; j < 8; j++) {
        p0 += acc[j] * wreg[j][0]; p1 += acc[j] * wreg[j][1];
        p2 += acc[j] * wreg[j][2]; p3 += acc[j] * wreg[j][3];
    }
#pragma unroll
    for (int s = 1; s <= 8; s <<= 1) {
        p0 += __shfl_xor(p0, s); p1 += __shfl_xor(p1, s);
        p2 += __shfl_xor(p2, s); p3 += __shfl_xor(p3, s);
    }
    if (c16 < 4) {
        float zv = (c16 == 0) ? p0 : (c16 == 1) ? p1 : (c16 == 2) ? p2 : p3;
        Z[(size_t)node * NCLS + g * 4 + c16] = zv;
    }
}

// ---------------- Layer-2 agg: 4-lane-group Z-row gather, wave per node ----------------
// r4 = lane&3 owns features r4*4..+3; g = lane>>2 is edge slot (16 edges/load).
__global__ __launch_bounds__(256) void agg2_kernel(const float4* __restrict__ Z4,
                                                   const int2* __restrict__ csr_sw,
                                                   const int* __restrict__ offs,
                                                   const int* __restrict__ part,
                                                   const float* __restrict__ dinv,
                                                   const float4* __restrict__ bc2q,
                                                   float4* __restrict__ out4) {
    int wv = threadIdx.x >> 6, l = threadIdx.x & 63;
    int node = blockIdx.x * 4 + wv;            // 12500*4 == 50000
    int beg = offs[node] + part[node >> 8];
    int end = offs[node + 1] + part[(node + 1) >> 8];
    float di = dinv[node];
    int r4 = l & 3, g = l >> 2;

    float4 acc = make_float4(0.f, 0.f, 0.f, 0.f);
    int e = beg;
    for (; e + 16 <= end; e += 16) {
        int2 sw = csr_sw[e + g];
        float4 v = Z4[(size_t)sw.x * 4 + r4];
        float wgt = __int_as_float(sw.y) * di;
        acc.x += v.x * wgt; acc.y += v.y * wgt;
        acc.z += v.z * wgt; acc.w += v.w * wgt;
    }
    if (e < end) {                             // one masked round covers <=15 leftovers
        int ee = e + g;
        int idx = (ee < end) ? ee : (end - 1);
        int2 sw = csr_sw[idx];
        float wgt = (ee < end) ? __int_as_float(sw.y) * di : 0.f;
        float4 v = Z4[(size_t)sw.x * 4 + r4];
        acc.x += v.x * wgt; acc.y += v.y * wgt;
        acc.z += v.z * wgt; acc.w += v.w * wgt;
    }
#pragma unroll
    for (int s = 4; s <= 32; s <<= 1) {
        acc.x += __shfl_xor(acc.x, s); acc.y += __shfl_xor(acc.y, s);
        acc.z += __shfl_xor(acc.z, s); acc.w += __shfl_xor(acc.w, s);
    }
    // self + bias
    float4 sv = Z4[(size_t)node * 4 + r4];
    float n2 = di * di;
    float4 b = bc2q[r4];
    acc.x += sv.x * n2 + b.x; acc.y += sv.y * n2 + b.y;
    acc.z += sv.z * n2 + b.z; acc.w += sv.w * n2 + b.w;
    if (l < 4) out4[(size_t)node * 4 + r4] = acc;
}

// ---------------- Launch ----------------
extern "C" void kernel_launch(void* const* d_in, const int* in_sizes, int n_in,
                              void* d_out, int out_size, void* d_ws, size_t ws_size,
                              hipStream_t stream) {
    const float* seq   = (const float*)d_in[0];
    const int*   eidx  = (const int*)d_in[1];
    const float* W1    = (const float*)d_in[2];
    const float* b1    = (const float*)d_in[3];
    const float* gamma = (const float*)d_in[4];
    const float* beta  = (const float*)d_in[5];
    const float* rmean = (const float*)d_in[6];
    const float* rvar  = (const float*)d_in[7];
    const float* W2    = (const float*)d_in[8];
    const float* b2    = (const float*)d_in[9];
    const float* Wc    = (const float*)d_in[10];
    const float* bc    = (const float*)d_in[11];

    const int* src = eidx;            // edge_index[0]
    const int* dst = eidx + N_EDGES;  // edge_index[1]

    char* ws = (char*)d_ws;
    size_t off = 0;
    auto alloc = [&](size_t bytes) -> void* {
        void* p = ws + off;
        off = (off + bytes + 255) & ~(size_t)255;
        return p;
    };
    int*    degcur   = (int*)alloc((size_t)2 * N_NODES * 4);  // deg | cursor (one memset)
    int*    deg      = degcur;
    int*    cursor   = degcur + N_NODES;
    int*    offs     = (int*)alloc((N_NODES + 1) * 4);
    int*    partials = (int*)alloc(256 * 4);
    float*  dinv     = (float*)alloc(N_NODES * 4);
    int2*   csr_sw   = (int2*)alloc((size_t)N_EDGES * 8);
    float*  W2c      = (float*)alloc(FDIM * NCLS * 4);
    float*  bc2      = (float*)alloc(NCLS * 4);
    float4* fusedq   = (float4*)alloc(64 * 16);
    unsigned* bufA   = (unsigned*)alloc((size_t)N_NODES * (FDIM / 2) * 4);  // bf16 packed
    float*  Zbuf     = (float*)alloc((size_t)N_NODES * NCLS * 4);

    const int NB_N = (N_NODES + 255) / 256;   // 196
    const int NB_E = (N_EDGES + 255) / 256;   // 2500

    hipMemsetAsync(degcur, 0, (size_t)2 * N_NODES * 4, stream);
    count_deg_kernel<<<NB_E, 256, 0, stream>>>(dst, deg);
    scan_block_kernel<<<NB_N, 256, 0, stream>>>(deg, offs, partials, dinv);
    scan_partials_kernel<<<1, 256, 0, stream>>>(partials, NB_N);
    fill_csr_kernel<<<NB_E, 256, 0, stream>>>(src, dst, offs, partials, dinv,
                                              cursor, csr_sw);
    fold_w_kernel<<<8, 256, 0, stream>>>(W2, Wc, b1, b2, bc, gamma, beta, rmean, rvar,
                                         W2c, bc2, fusedq);

    gemm128_kernel<<<(N_NODES + 63) / 64, 256, 0, stream>>>(seq, W1, bufA, N_NODES);
    agg1_kernel<<<N_NODES / 4, 256, 0, stream>>>((const uint4*)bufA, csr_sw, offs, partials,
                                                 dinv, fusedq, W2c, Zbuf);
    agg2_kernel<<<N_NODES / 4, 256, 0, stream>>>((const float4*)Zbuf, csr_sw, offs, partials,
                                                 dinv, (const float4*)bc2, (float4*)d_out);
}

// Round 5
// 250.135 us; speedup vs baseline: 1.1554x; 1.1554x over previous
//
#include <hip/hip_runtime.h>
#include <math.h>

#define N_NODES 50000
#define N_EDGES 640000
#define FDIM 128
#define NCLS 16
#define BN_EPS 1e-5f

// ---- bf16 pack/unpack (RNE) ----
__device__ __forceinline__ unsigned pack_bf16x2(float lo, float hi) {
    unsigned ul = __float_as_uint(lo);
    unsigned uh = __float_as_uint(hi);
    ul += 0x7fff + ((ul >> 16) & 1);
    uh += 0x7fff + ((uh >> 16) & 1);
    return (ul >> 16) | (uh & 0xffff0000u);
}
__device__ __forceinline__ float bf_lo(unsigned u) { return __uint_as_float(u << 16); }
__device__ __forceinline__ float bf_hi(unsigned u) { return __uint_as_float(u & 0xffff0000u); }

// ---------------- CSR build ----------------

__global__ __launch_bounds__(256) void count_deg_kernel(const int* __restrict__ dst, int* __restrict__ deg) {
    int gid = blockIdx.x * 256 + threadIdx.x;
    if (gid < N_EDGES) atomicAdd(&deg[dst[gid]], 1);
}

__global__ __launch_bounds__(256) void scan_block_kernel(const int* __restrict__ deg,
                                                         int* __restrict__ offs,
                                                         int* __restrict__ partials,
                                                         float* __restrict__ dinv) {
    __shared__ int s[256];
    int tid = threadIdx.x;
    int gid = blockIdx.x * 256 + tid;
    int v = (gid < N_NODES) ? deg[gid] : 0;
    if (gid < N_NODES) dinv[gid] = rsqrtf((float)(v + 1));  // +1 self loop
    s[tid] = v;
    __syncthreads();
    for (int off = 1; off < 256; off <<= 1) {
        int t = (tid >= off) ? s[tid - off] : 0;
        __syncthreads();
        s[tid] += t;
        __syncthreads();
    }
    if (gid <= N_NODES) offs[gid] = s[tid] - v;   // block-local exclusive
    if (tid == 255) partials[blockIdx.x] = s[255];
}

__global__ __launch_bounds__(256) void scan_partials_kernel(int* __restrict__ partials, int nb) {
    __shared__ int s[256];
    int tid = threadIdx.x;
    int v = (tid < nb) ? partials[tid] : 0;
    s[tid] = v;
    __syncthreads();
    for (int off = 1; off < 256; off <<= 1) {
        int t = (tid >= off) ? s[tid - off] : 0;
        __syncthreads();
        s[tid] += t;
        __syncthreads();
    }
    if (tid < nb) partials[tid] = s[tid] - v;
}

__global__ __launch_bounds__(256) void fill_csr_kernel(const int* __restrict__ src,
                                                       const int* __restrict__ dst,
                                                       const int* __restrict__ offs,
                                                       const int* __restrict__ part,
                                                       const float* __restrict__ dinv,
                                                       int* __restrict__ cursor,
                                                       int2* __restrict__ csr_sw) {
    int gid = blockIdx.x * 256 + threadIdx.x;
    if (gid < N_EDGES) {
        int d = dst[gid];
        int s = src[gid];
        int pos = offs[d] + part[d >> 8] + atomicAdd(&cursor[d], 1);
        csr_sw[pos] = make_int2(s, __float_as_int(dinv[s]));
    }
}

// ---------------- fold: W2c = W2@Wc, bc2 = b2@Wc + bc, fused BN affine ----------------
__global__ __launch_bounds__(256) void fold_w_kernel(const float* __restrict__ W2,
                                                     const float* __restrict__ Wc,
                                                     const float* __restrict__ b1,
                                                     const float* __restrict__ b2,
                                                     const float* __restrict__ bc,
                                                     const float* __restrict__ gamma,
                                                     const float* __restrict__ beta,
                                                     const float* __restrict__ rmean,
                                                     const float* __restrict__ rvar,
                                                     float* __restrict__ W2c,
                                                     float* __restrict__ bc2,
                                                     float4* __restrict__ fusedq) {
    int gid = blockIdx.x * 256 + threadIdx.x;  // 0..2047
    int r = gid >> 4, c = gid & 15;
    float acc = 0.f;
#pragma unroll 8
    for (int k = 0; k < 128; k++) acc += W2[r * 128 + k] * Wc[k * 16 + c];
    W2c[gid] = acc;
    if (blockIdx.x == 0) {
        int tid = threadIdx.x;
        if (tid < 16) {
            float a = bc[tid];
            for (int k = 0; k < 128; k++) a += b2[k] * Wc[k * 16 + tid];
            bc2[tid] = a;
        }
        if (tid < 64) {
            int c0 = tid * 2, c1 = c0 + 1;
            float sc0 = gamma[c0] * rsqrtf(rvar[c0] + BN_EPS);
            float sc1 = gamma[c1] * rsqrtf(rvar[c1] + BN_EPS);
            float sh0 = (b1[c0] - rmean[c0]) * sc0 + beta[c0];
            float sh1 = (b1[c1] - rmean[c1]) * sc1 + beta[c1];
            fusedq[tid] = make_float4(sc0, sh0, sc1, sh1);
        }
    }
}

// ---------------- GEMM 50000x128 @ 128x128 -> bf16 out ----------------
__global__ __launch_bounds__(256) void gemm128_kernel(const float* __restrict__ X,
                                                      const float* __restrict__ W,
                                                      unsigned* __restrict__ Yb, int M) {
    __shared__ float sX[64 * 33];
    __shared__ float sW[32 * 128];
    int tid = threadIdx.x;
    int r0 = blockIdx.x * 64;
    int colg = tid & 15, rowt = tid >> 4;

    float acc[4][8];
#pragma unroll
    for (int i = 0; i < 4; i++)
#pragma unroll
        for (int j = 0; j < 8; j++) acc[i][j] = 0.f;

    const float4* X4 = (const float4*)X;
    const float4* W4 = (const float4*)W;
    float4* sW4 = (float4*)sW;

#pragma unroll
    for (int kt = 0; kt < 4; kt++) {
#pragma unroll
        for (int i = 0; i < 2; i++) {
            int idx = tid + i * 256;
            int row = idx >> 3, k4 = idx & 7;
            float4 v = make_float4(0.f, 0.f, 0.f, 0.f);
            if (r0 + row < M) v = X4[(size_t)(r0 + row) * 32 + kt * 8 + k4];
            float* p = &sX[row * 33 + k4 * 4];
            p[0] = v.x; p[1] = v.y; p[2] = v.z; p[3] = v.w;
        }
#pragma unroll
        for (int i = 0; i < 4; i++) {
            int idx = tid + i * 256;
            int kk = idx >> 5, c4 = idx & 31;
            sW4[kk * 32 + c4] = W4[(size_t)(kt * 32 + kk) * 32 + c4];
        }
        __syncthreads();

#pragma unroll 8
        for (int k = 0; k < 32; k++) {
            float4 w0 = sW4[k * 32 + colg * 2];
            float4 w1 = sW4[k * 32 + colg * 2 + 1];
            float xs[4];
#pragma unroll
            for (int i = 0; i < 4; i++) xs[i] = sX[(rowt * 4 + i) * 33 + k];
#pragma unroll
            for (int i = 0; i < 4; i++) {
                acc[i][0] += xs[i] * w0.x; acc[i][1] += xs[i] * w0.y;
                acc[i][2] += xs[i] * w0.z; acc[i][3] += xs[i] * w0.w;
                acc[i][4] += xs[i] * w1.x; acc[i][5] += xs[i] * w1.y;
                acc[i][6] += xs[i] * w1.z; acc[i][7] += xs[i] * w1.w;
            }
        }
        __syncthreads();
    }

#pragma unroll
    for (int i = 0; i < 4; i++) {
        int row = r0 + rowt * 4 + i;
        if (row < M) {
            uint4 pv;
            pv.x = pack_bf16x2(acc[i][0], acc[i][1]);
            pv.y = pack_bf16x2(acc[i][2], acc[i][3]);
            pv.z = pack_bf16x2(acc[i][4], acc[i][5]);
            pv.w = pack_bf16x2(acc[i][6], acc[i][7]);
            *((uint4*)(Yb + (size_t)row * 64 + colg * 4)) = pv;
        }
    }
}

// ---------------- Layer-1 agg: full-wave row gather (1 segment/instr) + BN + ReLU + @W2c -> Z ----
// Lane l owns dword l of the 256 B bf16 row. Edge indices go through the scalar pipe
// (readfirstlane -> s_load), row loads are the only VMEM traffic. 8 rows in flight.
__global__ __launch_bounds__(256) void agg1_kernel(const unsigned* __restrict__ Hb,
                                                   const int2* __restrict__ csr_sw,
                                                   const int* __restrict__ offs,
                                                   const int* __restrict__ part,
                                                   const float* __restrict__ dinv,
                                                   const float4* __restrict__ fusedq,
                                                   const float* __restrict__ W2c,
                                                   float* __restrict__ Z) {
    __shared__ float sH[4][128];
    int w = threadIdx.x >> 6, l = threadIdx.x & 63;
    int node = blockIdx.x * 4 + w;             // 12500*4 == 50000
    int beg = __builtin_amdgcn_readfirstlane(offs[node] + part[node >> 8]);
    int end = __builtin_amdgcn_readfirstlane(offs[node + 1] + part[(node + 1) >> 8]);
    float di = dinv[node];

    // W2c slice for the fused epilogue: lane (c=l&15, q=l>>4) owns k = q*32..+31 of column c
    int c = l & 15, q = l >> 4;
    float wreg[32];
#pragma unroll
    for (int i = 0; i < 32; i++) wreg[i] = W2c[(q * 32 + i) * 16 + c];

    unsigned hv = Hb[(size_t)node * 64 + l];
    float n2 = di * di;
    float acc0 = bf_lo(hv) * n2, acc1 = bf_hi(hv) * n2;  // self loop

    int e = beg;
    for (; e + 8 <= end; e += 8) {             // 8 full-wave row loads in flight
        int2 a0 = csr_sw[e];     int2 a1 = csr_sw[e + 1];
        int2 a2 = csr_sw[e + 2]; int2 a3 = csr_sw[e + 3];
        int2 a4 = csr_sw[e + 4]; int2 a5 = csr_sw[e + 5];
        int2 a6 = csr_sw[e + 6]; int2 a7 = csr_sw[e + 7];
        unsigned u0 = Hb[(size_t)a0.x * 64 + l];
        unsigned u1 = Hb[(size_t)a1.x * 64 + l];
        unsigned u2 = Hb[(size_t)a2.x * 64 + l];
        unsigned u3 = Hb[(size_t)a3.x * 64 + l];
        unsigned u4 = Hb[(size_t)a4.x * 64 + l];
        unsigned u5 = Hb[(size_t)a5.x * 64 + l];
        unsigned u6 = Hb[(size_t)a6.x * 64 + l];
        unsigned u7 = Hb[(size_t)a7.x * 64 + l];
        float w0 = __int_as_float(a0.y) * di, w1 = __int_as_float(a1.y) * di;
        float w2 = __int_as_float(a2.y) * di, w3 = __int_as_float(a3.y) * di;
        float w4 = __int_as_float(a4.y) * di, w5 = __int_as_float(a5.y) * di;
        float w6 = __int_as_float(a6.y) * di, w7 = __int_as_float(a7.y) * di;
        acc0 += bf_lo(u0) * w0 + bf_lo(u1) * w1 + bf_lo(u2) * w2 + bf_lo(u3) * w3
              + bf_lo(u4) * w4 + bf_lo(u5) * w5 + bf_lo(u6) * w6 + bf_lo(u7) * w7;
        acc1 += bf_hi(u0) * w0 + bf_hi(u1) * w1 + bf_hi(u2) * w2 + bf_hi(u3) * w3
              + bf_hi(u4) * w4 + bf_hi(u5) * w5 + bf_hi(u6) * w6 + bf_hi(u7) * w7;
    }
    for (; e < end; e++) {                     // exact tail, no dummy loads
        int2 a = csr_sw[e];
        unsigned u = Hb[(size_t)a.x * 64 + l];
        float wt = __int_as_float(a.y) * di;
        acc0 += bf_lo(u) * wt;
        acc1 += bf_hi(u) * wt;
    }

    // fused BN affine + ReLU (lane l holds features 2l, 2l+1)
    float4 qv = fusedq[l];
    float a0 = fmaxf(acc0 * qv.x + qv.y, 0.f);
    float a1 = fmaxf(acc1 * qv.z + qv.w, 0.f);

    // in-wave transpose through LDS (wave-private region, no barrier)
    ((float2*)sH[w])[l] = make_float2(a0, a1);
    float z = 0.f;
    const float4* row4 = (const float4*)&sH[w][q * 32];
#pragma unroll
    for (int i = 0; i < 8; i++) {
        float4 v = row4[i];
        z += v.x * wreg[i * 4] + v.y * wreg[i * 4 + 1] + v.z * wreg[i * 4 + 2] + v.w * wreg[i * 4 + 3];
    }
    z += __shfl_xor(z, 16);
    z += __shfl_xor(z, 32);
    if (l < 16) Z[(size_t)node * NCLS + l] = z;
}

// ---------------- Layer-2 agg: 16-lane-group Z-row gather (64 B, 4 segments/wave) ----------------
__global__ __launch_bounds__(256) void agg2_kernel(const float* __restrict__ Z,
                                                   const int2* __restrict__ csr_sw,
                                                   const int* __restrict__ offs,
                                                   const int* __restrict__ part,
                                                   const float* __restrict__ dinv,
                                                   const float* __restrict__ bc2,
                                                   float* __restrict__ out) {
    int grp = threadIdx.x >> 4, c = threadIdx.x & 15;
    int node = blockIdx.x * 16 + grp;          // 3125*16 == 50000
    int beg = offs[node] + part[node >> 8];
    int end = offs[node + 1] + part[(node + 1) >> 8];
    float di = dinv[node];

    float acc = Z[(size_t)node * NCLS + c] * di * di;
    int e = beg;
    for (; e + 4 <= end; e += 4) {
        int2 a0 = csr_sw[e],     a1 = csr_sw[e + 1];
        int2 a2 = csr_sw[e + 2], a3 = csr_sw[e + 3];
        float v0 = Z[(size_t)a0.x * NCLS + c];
        float v1 = Z[(size_t)a1.x * NCLS + c];
        float v2 = Z[(size_t)a2.x * NCLS + c];
        float v3 = Z[(size_t)a3.x * NCLS + c];
        acc += v0 * (__int_as_float(a0.y) * di) + v1 * (__int_as_float(a1.y) * di)
             + v2 * (__int_as_float(a2.y) * di) + v3 * (__int_as_float(a3.y) * di);
    }
    for (; e < end; e++) {
        int2 a = csr_sw[e];
        acc += Z[(size_t)a.x * NCLS + c] * (__int_as_float(a.y) * di);
    }
    out[(size_t)node * NCLS + c] = acc + bc2[c];
}

// ---------------- Launch ----------------
extern "C" void kernel_launch(void* const* d_in, const int* in_sizes, int n_in,
                              void* d_out, int out_size, void* d_ws, size_t ws_size,
                              hipStream_t stream) {
    const float* seq   = (const float*)d_in[0];
    const int*   eidx  = (const int*)d_in[1];
    const float* W1    = (const float*)d_in[2];
    const float* b1    = (const float*)d_in[3];
    const float* gamma = (const float*)d_in[4];
    const float* beta  = (const float*)d_in[5];
    const float* rmean = (const float*)d_in[6];
    const float* rvar  = (const float*)d_in[7];
    const float* W2    = (const float*)d_in[8];
    const float* b2    = (const float*)d_in[9];
    const float* Wc    = (const float*)d_in[10];
    const float* bc    = (const float*)d_in[11];

    const int* src = eidx;            // edge_index[0]
    const int* dst = eidx + N_EDGES;  // edge_index[1]

    char* ws = (char*)d_ws;
    size_t off = 0;
    auto alloc = [&](size_t bytes) -> void* {
        void* p = ws + off;
        off = (off + bytes + 255) & ~(size_t)255;
        return p;
    };
    int*    degcur   = (int*)alloc((size_t)2 * N_NODES * 4);  // deg | cursor (one memset)
    int*    deg      = degcur;
    int*    cursor   = degcur + N_NODES;
    int*    offs     = (int*)alloc((N_NODES + 1) * 4);
    int*    partials = (int*)alloc(256 * 4);
    float*  dinv     = (float*)alloc(N_NODES * 4);
    int2*   csr_sw   = (int2*)alloc((size_t)N_EDGES * 8);
    float*  W2c      = (float*)alloc(FDIM * NCLS * 4);
    float*  bc2      = (float*)alloc(NCLS * 4);
    float4* fusedq   = (float4*)alloc(64 * 16);
    unsigned* bufA   = (unsigned*)alloc((size_t)N_NODES * (FDIM / 2) * 4);  // bf16 packed
    float*  Zbuf     = (float*)alloc((size_t)N_NODES * NCLS * 4);

    const int NB_N = (N_NODES + 255) / 256;   // 196
    const int NB_E = (N_EDGES + 255) / 256;   // 2500

    hipMemsetAsync(degcur, 0, (size_t)2 * N_NODES * 4, stream);
    count_deg_kernel<<<NB_E, 256, 0, stream>>>(dst, deg);
    scan_block_kernel<<<NB_N, 256, 0, stream>>>(deg, offs, partials, dinv);
    scan_partials_kernel<<<1, 256, 0, stream>>>(partials, NB_N);
    fill_csr_kernel<<<NB_E, 256, 0, stream>>>(src, dst, offs, partials, dinv,
                                              cursor, csr_sw);
    fold_w_kernel<<<8, 256, 0, stream>>>(W2, Wc, b1, b2, bc, gamma, beta, rmean, rvar,
                                         W2c, bc2, fusedq);

    gemm128_kernel<<<(N_NODES + 63) / 64, 256, 0, stream>>>(seq, W1, bufA, N_NODES);
    agg1_kernel<<<N_NODES / 4, 256, 0, stream>>>(bufA, csr_sw, offs, partials,
                                                 dinv, fusedq, W2c, Zbuf);
    agg2_kernel<<<N_NODES / 16, 256, 0, stream>>>(Zbuf, csr_sw, offs, partials,
                                                  dinv, bc2, (float*)d_out);
}